// Round 4
// baseline (54.822 us; speedup 1.0000x reference)
//
#include <hip/hip_runtime.h>

#define WPTS 801
#define ROWS 16
#define NT 256

struct c2 { float x, y; };

__device__ __forceinline__ c2 c_add(c2 a, c2 b) { return {a.x + b.x, a.y + b.y}; }
__device__ __forceinline__ c2 c_sub(c2 a, c2 b) { return {a.x - b.x, a.y - b.y}; }
__device__ __forceinline__ c2 c_div(c2 a, c2 b) {
    float inv = 1.0f / (b.x * b.x + b.y * b.y);
    return {(a.x * b.x + a.y * b.y) * inv, (a.y * b.x - a.x * b.y) * inv};
}

__global__ __launch_bounds__(NT)
void kla_tmm_kernel(const float* __restrict__ d_phys,
                    const float* __restrict__ nSi_f,
                    const float* __restrict__ nSiO2_f,
                    const float* __restrict__ nSi3N4_f,
                    const float* __restrict__ lam,
                    float* __restrict__ out,
                    int B)
{
    const int nRowBlks = (B + ROWS - 1) / ROWS;
    const int t = blockIdx.x * NT + threadIdx.x;
    if (t >= nRowBlks * WPTS) return;

    const int w = t % WPTS;
    const int row0 = (t / WPTS) * ROWS;
    const int nrows = min(ROWS, B - row0);

    // ---- Layout-robust complex reads (same detection as the passing r2/r3) ----
    const bool ilv = (nSiO2_f[1] == 0.0f);
    float nSx, nSy, nOx, nOy, nNx, nNy;
    if (ilv) {
        nSx = nSi_f[2 * w];    nSy = nSi_f[2 * w + 1];
        nOx = nSiO2_f[2 * w];  nOy = nSiO2_f[2 * w + 1];
        nNx = nSi3N4_f[2 * w]; nNy = nSi3N4_f[2 * w + 1];
    } else {
        nSx = nSi_f[w];    nSy = 0.0f;
        nOx = nSiO2_f[w];  nOy = 0.0f;
        nNx = nSi3N4_f[w]; nNy = 0.0f;
    }

    const float k0 = 6.28318530717958647692f / lam[w];
    const bool realn = (nOy == 0.0f) && (nNy == 0.0f) && (nSy == 0.0f);

    if (realn && nrows == ROWS) {
        // ======== real-index fast path, 2-row ILP + d prefetch ========
        const float rAO  = (1.0f - nOx) / (1.0f + nOx);
        const float rON  = (nOx - nNx) / (nOx + nNx);
        const float rNO  = -rON;
        const float rOSi = (nOx - nSx) / (nOx + nSx);
        const float kO = k0 * nOx;
        const float kN = k0 * nNx;

        const float* base = d_phys + (size_t)row0 * 7;
        float* orow = out + (size_t)row0 * WPTS + w;

        float ca[7], cb[7], na[7], nb[7];
        #pragma unroll
        for (int j = 0; j < 7; ++j) { ca[j] = base[j]; cb[j] = base[7 + j]; }

        #pragma unroll
        for (int p = 0; p < ROWS / 2; ++p) {
            // prefetch next pair's thicknesses (hidden under this pair's compute)
            if (p < ROWS / 2 - 1) {
                const float* nxt = base + (size_t)(2 * p + 2) * 7;
                #pragma unroll
                for (int j = 0; j < 7; ++j) { na[j] = nxt[j]; nb[j] = nxt[7 + j]; }
            }

            float u0xA = 1.0f, u0yA = 0.0f, u1xA = rOSi, u1yA = 0.0f;
            float u0xB = 1.0f, u0yB = 0.0f, u1xB = rOSi, u1yB = 0.0f;

            #pragma unroll
            for (int i = 7; i >= 1; --i) {
                const float kk = (i & 1) ? kO : kN;
                const float r  = (i == 1) ? rAO : ((i & 1) ? rNO : rON);
                const float aA = ca[i - 1] * kk;
                const float aB = cb[i - 1] * kk;
                float sA, cA, sB, cB;
                __sincosf(aA, &sA, &cA);
                __sincosf(aB, &sB, &cB);

                // chain A: rotate then mix
                const float t0xA = u0xA * cA + u0yA * sA;
                const float t0yA = u0yA * cA - u0xA * sA;
                const float t1xA = u1xA * cA - u1yA * sA;
                const float t1yA = u1yA * cA + u1xA * sA;
                u0xA = t0xA + r * t1xA;
                u0yA = t0yA + r * t1yA;
                u1xA = t1xA + r * t0xA;
                u1yA = t1yA + r * t0yA;

                // chain B (independent — fills A's latency)
                const float t0xB = u0xB * cB + u0yB * sB;
                const float t0yB = u0yB * cB - u0xB * sB;
                const float t1xB = u1xB * cB - u1yB * sB;
                const float t1yB = u1yB * cB + u1xB * sB;
                u0xB = t0xB + r * t1xB;
                u0yB = t0yB + r * t1yB;
                u1xB = t1xB + r * t0xB;
                u1yB = t1yB + r * t0yB;
            }

            const float numA = u1xA * u1xA + u1yA * u1yA;
            const float denA = u0xA * u0xA + u0yA * u0yA;
            const float numB = u1xB * u1xB + u1yB * u1yB;
            const float denB = u0xB * u0xB + u0yB * u0yB;
            orow[(size_t)(2 * p) * WPTS]     = numA * __builtin_amdgcn_rcpf(denA);
            orow[(size_t)(2 * p + 1) * WPTS] = numB * __builtin_amdgcn_rcpf(denB);

            #pragma unroll
            for (int j = 0; j < 7; ++j) { ca[j] = na[j]; cb[j] = nb[j]; }
        }
    } else {
        // ======== general complex path (round-2 code, known correct) ========
        const c2 nA = {1.0f, 0.0f};
        const c2 nO = {nOx, nOy}, nN = {nNx, nNy}, nS = {nSx, nSy};
        const c2 rAO  = c_div(c_sub(nA, nO), c_add(nA, nO));
        const c2 rON  = c_div(c_sub(nO, nN), c_add(nO, nN));
        const c2 rNO  = {-rON.x, -rON.y};
        const c2 rOSi = c_div(c_sub(nO, nS), c_add(nO, nS));
        const c2 kO = {k0 * nO.x, k0 * nO.y};
        const c2 kN = {k0 * nN.x, k0 * nN.y};

        for (int rr = 0; rr < nrows; ++rr) {
            const int row = row0 + rr;
            const float* dd = d_phys + (size_t)row * 7;

            c2 u0 = {1.0f, 0.0f};
            c2 u1 = rOSi;

            #pragma unroll
            for (int i = 7; i >= 1; --i) {
                const float d = dd[i - 1];
                const c2 kk = (i & 1) ? kO : kN;
                const float alpha = kk.x * d;
                const float beta  = kk.y * d;
                float s, c;
                __sincosf(alpha, &s, &c);
                const float ep = __expf(beta);
                const float em = __expf(-beta);

                c2 v;
                v.x = ep * (u0.x * c + u0.y * s);
                v.y = ep * (u0.y * c - u0.x * s);
                u0 = v;
                v.x = em * (u1.x * c - u1.y * s);
                v.y = em * (u1.y * c + u1.x * s);
                u1 = v;

                const c2 ri = (i == 1) ? rAO : ((i & 1) ? rNO : rON);
                c2 w0, w1;
                w0.x = u0.x + ri.x * u1.x - ri.y * u1.y;
                w0.y = u0.y + ri.x * u1.y + ri.y * u1.x;
                w1.x = u1.x + ri.x * u0.x - ri.y * u0.y;
                w1.y = u1.y + ri.x * u0.y + ri.y * u0.x;
                u0 = w0; u1 = w1;
            }

            out[(size_t)row * WPTS + w] =
                (u1.x * u1.x + u1.y * u1.y) / (u0.x * u0.x + u0.y * u0.y);
        }
    }
}

extern "C" void kernel_launch(void* const* d_in, const int* in_sizes, int n_in,
                              void* d_out, int out_size, void* d_ws, size_t ws_size,
                              hipStream_t stream) {
    const float* d_phys  = (const float*)d_in[0];
    const float* nSi     = (const float*)d_in[1];
    const float* nSiO2   = (const float*)d_in[2];
    const float* nSi3N4  = (const float*)d_in[3];
    const float* lam     = (const float*)d_in[4];
    float* out = (float*)d_out;

    const int B = in_sizes[0] / 7;
    const int nRowBlks = (B + ROWS - 1) / ROWS;
    const int nTasks = nRowBlks * WPTS;
    const int grid = (nTasks + NT - 1) / NT;

    kla_tmm_kernel<<<grid, NT, 0, stream>>>(
        d_phys, nSi, nSiO2, nSi3N4, lam, out, B);
}

// Round 5
// 51.903 us; speedup vs baseline: 1.0562x; 1.0562x over previous
//
#include <hip/hip_runtime.h>

#define WPTS 801
#define ROWS 16
#define NT 256

typedef float v2 __attribute__((ext_vector_type(2)));

struct c2 { float x, y; };

__device__ __forceinline__ c2 c_addc(c2 a, c2 b) { return {a.x + b.x, a.y + b.y}; }
__device__ __forceinline__ c2 c_subc(c2 a, c2 b) { return {a.x - b.x, a.y - b.y}; }
__device__ __forceinline__ c2 c_divc(c2 a, c2 b) {
    float inv = 1.0f / (b.x * b.x + b.y * b.y);
    return {(a.x * b.x + a.y * b.y) * inv, (a.y * b.x - a.x * b.y) * inv};
}

// sin(pi*t), cos(pi*t) for t in [-0.5, 0.5] — packed-friendly Taylor polys.
// sin: max err ~3.5e-6, cos: ~2.5e-5 (both << bf16 compare floor).
__device__ __forceinline__ void sincos_pi_v2(v2 t, v2& s, v2& c) {
    const float A1 =  3.14159265358979f;
    const float A3 = -5.16771278004997f;
    const float A5 =  2.55016403987735f;
    const float A7 = -0.59926452932079f;
    const float A9 =  0.08214588661113f;
    const float C2 = -4.93480220054468f;
    const float C4 =  4.05871212641677f;
    const float C6 = -1.33526276885459f;
    const float C8 =  0.23533063035889f;
    v2 q = t * t;
    v2 ps = A7 + q * A9;
    ps = A5 + q * ps;
    ps = A3 + q * ps;
    ps = A1 + q * ps;
    s = t * ps;
    v2 pc = C6 + q * C8;
    pc = C4 + q * pc;
    pc = C2 + q * pc;
    c = 1.0f + q * pc;
}

__global__ __launch_bounds__(NT)
void kla_tmm_kernel(const float* __restrict__ d_phys,
                    const float* __restrict__ nSi_f,
                    const float* __restrict__ nSiO2_f,
                    const float* __restrict__ nSi3N4_f,
                    const float* __restrict__ lam,
                    float* __restrict__ out,
                    int B)
{
    const int nRowBlks = (B + ROWS - 1) / ROWS;
    const int t = blockIdx.x * NT + threadIdx.x;
    if (t >= nRowBlks * WPTS) return;

    const int w = t % WPTS;
    const int row0 = (t / WPTS) * ROWS;
    const int nrows = min(ROWS, B - row0);

    // ---- Layout-robust complex reads (same detection as passing r2/r3) ----
    const bool ilv = (nSiO2_f[1] == 0.0f);
    float nSx, nSy, nOx, nOy, nNx, nNy;
    if (ilv) {
        nSx = nSi_f[2 * w];    nSy = nSi_f[2 * w + 1];
        nOx = nSiO2_f[2 * w];  nOy = nSiO2_f[2 * w + 1];
        nNx = nSi3N4_f[2 * w]; nNy = nSi3N4_f[2 * w + 1];
    } else {
        nSx = nSi_f[w];    nSy = 0.0f;
        nOx = nSiO2_f[w];  nOy = 0.0f;
        nNx = nSi3N4_f[w]; nNy = 0.0f;
    }

    const float k0 = 6.28318530717958647692f / lam[w];
    const bool realn = (nOy == 0.0f) && (nNy == 0.0f) && (nSy == 0.0f);

    if (realn && nrows == ROWS) {
        // ======== real-n fast path: packed f32, 2 rows per instruction ========
        const float rAO  = (1.0f - nOx) / (1.0f + nOx);
        const float rON  = (nOx - nNx) / (nOx + nNx);
        const float rNO  = -rON;
        const float rOSi = (nOx - nSx) / (nOx + nSx);
        const float invpi = 0.318309886183790672f;
        const float kOpi = k0 * nOx * invpi;   // (k0*n)/pi — nu = d * kpi
        const float kNpi = k0 * nNx * invpi;

        const float* base = d_phys + (size_t)row0 * 7;
        float* orow = out + (size_t)row0 * WPTS + w;

        #pragma unroll
        for (int p = 0; p < ROWS / 2; ++p) {
            const float* dA = base + (size_t)(2 * p) * 7;
            const float* dB = dA + 7;

            v2 u0x = {1.0f, 1.0f};
            v2 u0y = {0.0f, 0.0f};
            v2 u1x = {rOSi, rOSi};
            v2 u1y = {0.0f, 0.0f};

            #pragma unroll
            for (int i = 7; i >= 1; --i) {
                v2 d;
                d.x = dA[i - 1];
                d.y = dB[i - 1];
                const float kpi = (i & 1) ? kOpi : kNpi;
                const float r   = (i == 1) ? rAO : ((i & 1) ? rNO : rON);

                // alpha mod pi, in units of pi: tt = nu - rint(nu), |tt|<=0.5.
                // Parity sign of (c,s) flips the whole (u0,u1) state by -1 per
                // layer — cancels exactly in R = |u1|^2/|u0|^2, so it's dropped.
                v2 nu = d * kpi;
                v2 nn;
                nn.x = __builtin_rintf(nu.x);
                nn.y = __builtin_rintf(nu.y);
                v2 tt = nu - nn;
                v2 s, c;
                sincos_pi_v2(tt, s, c);

                // u0 *= (c - i s); u1 *= (c + i s)
                v2 t0x = u0x * c + u0y * s;
                v2 t0y = u0y * c - u0x * s;
                v2 t1x = u1x * c - u1y * s;
                v2 t1y = u1y * c + u1x * s;
                // interface (real r): u0' = u0 + r u1 ; u1' = u1 + r u0
                u0x = t0x + r * t1x;
                u0y = t0y + r * t1y;
                u1x = t1x + r * t0x;
                u1y = t1y + r * t0y;
            }

            v2 num = u1x * u1x + u1y * u1y;
            v2 den = u0x * u0x + u0y * u0y;
            orow[(size_t)(2 * p) * WPTS]     = num.x * __builtin_amdgcn_rcpf(den.x);
            orow[(size_t)(2 * p + 1) * WPTS] = num.y * __builtin_amdgcn_rcpf(den.y);
        }
    } else {
        // ======== general complex path (round-2 code, known correct) ========
        const c2 nA = {1.0f, 0.0f};
        const c2 nO = {nOx, nOy}, nN = {nNx, nNy}, nS = {nSx, nSy};
        const c2 rAO  = c_divc(c_subc(nA, nO), c_addc(nA, nO));
        const c2 rON  = c_divc(c_subc(nO, nN), c_addc(nO, nN));
        const c2 rNO  = {-rON.x, -rON.y};
        const c2 rOSi = c_divc(c_subc(nO, nS), c_addc(nO, nS));
        const c2 kO = {k0 * nO.x, k0 * nO.y};
        const c2 kN = {k0 * nN.x, k0 * nN.y};

        for (int rr = 0; rr < nrows; ++rr) {
            const int row = row0 + rr;
            const float* dd = d_phys + (size_t)row * 7;

            c2 u0 = {1.0f, 0.0f};
            c2 u1 = rOSi;

            #pragma unroll
            for (int i = 7; i >= 1; --i) {
                const float d = dd[i - 1];
                const c2 kk = (i & 1) ? kO : kN;
                const float alpha = kk.x * d;
                const float beta  = kk.y * d;
                float s, c;
                __sincosf(alpha, &s, &c);
                const float ep = __expf(beta);
                const float em = __expf(-beta);

                c2 v;
                v.x = ep * (u0.x * c + u0.y * s);
                v.y = ep * (u0.y * c - u0.x * s);
                u0 = v;
                v.x = em * (u1.x * c - u1.y * s);
                v.y = em * (u1.y * c + u1.x * s);
                u1 = v;

                const c2 ri = (i == 1) ? rAO : ((i & 1) ? rNO : rON);
                c2 w0, w1;
                w0.x = u0.x + ri.x * u1.x - ri.y * u1.y;
                w0.y = u0.y + ri.x * u1.y + ri.y * u1.x;
                w1.x = u1.x + ri.x * u0.x - ri.y * u0.y;
                w1.y = u1.y + ri.x * u0.y + ri.y * u0.x;
                u0 = w0; u1 = w1;
            }

            out[(size_t)row * WPTS + w] =
                (u1.x * u1.x + u1.y * u1.y) / (u0.x * u0.x + u0.y * u0.y);
        }
    }
}

extern "C" void kernel_launch(void* const* d_in, const int* in_sizes, int n_in,
                              void* d_out, int out_size, void* d_ws, size_t ws_size,
                              hipStream_t stream) {
    const float* d_phys  = (const float*)d_in[0];
    const float* nSi     = (const float*)d_in[1];
    const float* nSiO2   = (const float*)d_in[2];
    const float* nSi3N4  = (const float*)d_in[3];
    const float* lam     = (const float*)d_in[4];
    float* out = (float*)d_out;

    const int B = in_sizes[0] / 7;
    const int nRowBlks = (B + ROWS - 1) / ROWS;
    const int nTasks = nRowBlks * WPTS;
    const int grid = (nTasks + NT - 1) / NT;

    kla_tmm_kernel<<<grid, NT, 0, stream>>>(
        d_phys, nSi, nSiO2, nSi3N4, lam, out, B);
}